// Round 3
// baseline (128.565 us; speedup 1.0000x reference)
//
#include <hip/hip_runtime.h>
#include <math.h>

#ifndef M_PI
#define M_PI 3.14159265358979323846
#endif

namespace {
constexpr int B_ = 4;
constexpr int L_ = 2048;
constexpr int D_ = 64;
constexpr int H_ = 4;
constexpr int RB = 8;           // rows per block
constexpr int KT = 64;          // K-tile
constexpr int NTILE = L_ / KT;  // 32
constexpr int CAPC = 256;       // per-wave candidate capacity
constexpr int OUTW = D_ + H_ * D_;  // 320
constexpr int APS = 2064;       // A plane stride bytes (64*16*2 + 16 pad)
constexpr int ABYTES = 2 * APS;        // 4128
constexpr int BBYTES = KT * D_ * 2;    // 8192
constexpr int BUFB = ABYTES + BBYTES;  // 12320 per buffer
}

typedef __attribute__((ext_vector_type(8))) short bf16x8;
typedef __attribute__((ext_vector_type(4))) float f32x4;

__device__ __forceinline__ unsigned bf16_rne(float x) {
    unsigned u = __float_as_uint(x);
    return (u + 0x7fffu + ((u >> 16) & 1u)) >> 16;
}

// packed f32->bf16 RNE convert (gfx950 HW op)
__device__ __forceinline__ unsigned cvt_pk_bf16(float lo, float hi) {
    unsigned r;
    asm("v_cvt_pk_bf16_f32 %0, %1, %2" : "=v"(r) : "v"(lo), "v"(hi));
    return r;
}

#if defined(__has_builtin)
#if __has_builtin(__builtin_amdgcn_exp2f)
#define EXP2F(x) __builtin_amdgcn_exp2f(x)
#endif
#endif
#ifndef EXP2F
#define EXP2F(x) __expf((x) * 0.69314718055994531f)
#endif

// wait lgkmcnt(0) only (vmcnt=63, expcnt=7)
#define LDS_FENCE() __builtin_amdgcn_s_waitcnt(0xC07F)

// ---- fused prep + per-row threshold kernel.
// prep: inputs (B,L,D) fp32 -> ws bf16 k-major chunks (128 uints per block).
// thresh: one wave per row; rank-409/410 select (R13-verified math, gathers
// converted to ballot-compaction: order-independent, bit-identical stats).
// thD written to scratch slot out[row*OUTW + 319] (overwritten by posatt).
__global__ __launch_bounds__(256) void prep_thresh_kernel(
    const float* __restrict__ mesh,
    const float* __restrict__ inputs,
    char* __restrict__ ws,
    float* __restrict__ out)
{
    __shared__ unsigned s_hist[4][256];   // 4 KB (per-wave hist / c2)
    __shared__ float s_cand[4][256];      // 4 KB (per-wave candidates)

    const int t = threadIdx.x;
    const int l = t & 63;
    const int w = t >> 6;                 // 0..3
    const int blk = blockIdx.x;           // 2048

    // ---- prep part: one packed-uint conversion per thread (t<128)
    if (t < 128) {
        const unsigned u = (unsigned)blk * 128u + (unsigned)t;   // < 262144
        const int pb = u >> 16;             // batch
        const int rem = u & 65535;
        const int tile = rem >> 12;         // tile of 128 k
        const int idx = rem & 4095;
        const int n = idx & 63;
        const int kl = (idx >> 6) << 1;     // even k within tile128
        const float* inb = inputs + ((size_t)pb * L_ + tile * 128) * D_;
        char* wsb = ws + (size_t)pb * (L_ * D_ * 2) + tile * (128 * D_ * 2);
        const float x0 = inb[kl * D_ + n];
        const float x1 = inb[(kl + 1) * D_ + n];
        const int chunk = (kl >> 3) * 64 + n;
        const int e = kl & 7;
        *reinterpret_cast<unsigned*>(wsb + chunk * 16 + e * 2) =
            bf16_rne(x0) | (bf16_rne(x1) << 16);
    }

    // ---- thresh part: this wave's row
    const int row = blk * 4 + w;          // 0..8191
    const int b = row >> 11;
    const int rl = row & 2047;
    const float2* meshg = reinterpret_cast<const float2*>(mesh) + (size_t)b * L_;
    unsigned* hw = s_hist[w];
    float* cw = s_cand[w];
    const float2 me = meshg[rl];

    *reinterpret_cast<uint4*>(&hw[l * 4]) = make_uint4(0u, 0u, 0u, 0u);
    LDS_FENCE();
    #pragma unroll 4
    for (int it = 0; it < 32; ++it) {
        const int j = (it << 6) + l;
        const float2 mj = meshg[j];
        const float dx = __fsub_rn(me.x, mj.x);
        const float dy = __fsub_rn(me.y, mj.y);
        const float d = __fadd_rn(__fmul_rn(dx, dx), __fmul_rn(dy, dy));
        int bin = (int)(d * 128.0f); bin = bin < 255 ? bin : 255;
        atomicAdd(&hw[bin], 1u);
    }
    LDS_FENCE();
    // level-1 scan + crossings at ranks 409/410
    int lo, hi; unsigned base;
    {
        const uint4 hv = *reinterpret_cast<const uint4*>(&hw[l * 4]);
        const unsigned p0 = hv.x, p1 = p0 + hv.y, p2 = p1 + hv.z, p3 = p2 + hv.w;
        unsigned sc = p3;
        #pragma unroll
        for (int off = 1; off < 64; off <<= 1) {
            const unsigned uu = __shfl_up(sc, off);
            if (l >= off) sc += uu;
        }
        const unsigned eb = sc - p3;
        const unsigned cum[4] = {eb + p0, eb + p1, eb + p2, eb + p3};
        int flo = -1, fhi = -1; unsigned fbase = 0u;
        #pragma unroll
        for (int e = 0; e < 4; ++e) {
            const unsigned prev = e ? cum[e - 1] : eb;
            if (cum[e] > 409u && prev <= 409u) { flo = l * 4 + e; fbase = prev; }
            if (cum[e] > 410u && prev <= 410u) { fhi = l * 4 + e; }
        }
        const unsigned long long bmlo = __ballot(flo >= 0);
        const int srclo = (int)__builtin_ctzll(bmlo);
        lo = __shfl(flo, srclo);
        base = __shfl(fbase, srclo);
        const unsigned long long bmhi = __ballot(fhi >= 0);
        hi = __shfl(fhi, (int)__builtin_ctzll(bmhi));
    }
    // gather candidates from bins [lo,hi] — ballot compaction (no atomics)
    unsigned cbase = 0u;
    #pragma unroll 4
    for (int it = 0; it < 32; ++it) {
        const int j = (it << 6) + l;
        const float2 mj = meshg[j];
        const float dx = __fsub_rn(me.x, mj.x);
        const float dy = __fsub_rn(me.y, mj.y);
        const float d = __fadd_rn(__fmul_rn(dx, dx), __fmul_rn(dy, dy));
        int bin = (int)(d * 128.0f); bin = bin < 255 ? bin : 255;
        const bool pred = (bin >= lo && bin <= hi);
        const unsigned long long bm = __ballot(pred);
        if (pred) {
            const unsigned p = cbase + (unsigned)__popcll(bm & ((1ull << l) - 1ull));
            if (p < (unsigned)CAPC) cw[p] = d;
        }
        cbase += (unsigned)__popcll(bm);
    }
    LDS_FENCE();
    const int m = (int)min(cbase, (unsigned)CAPC);
    const unsigned k409 = 409u - base;      // rank within cw
    const unsigned k410 = 410u - base;
    // ---- level-2 refine: 256 sub-bins over candidate range
    const float lo_edge = (float)lo * 0.0078125f;          // lo/128, exact
    const float sc2 = 32768.0f / (float)(hi - lo + 1);     // 256*128/(span bins)
    *reinterpret_cast<uint4*>(&hw[l * 4]) = make_uint4(0u, 0u, 0u, 0u);
    LDS_FENCE();
    #pragma unroll 2
    for (int ci = l; ci < m; ci += 64) {
        const float v = cw[ci];
        int b2 = (int)(__fmul_rn(__fsub_rn(v, lo_edge), sc2));
        b2 = b2 < 255 ? b2 : 255; b2 = b2 > 0 ? b2 : 0;
        atomicAdd(&hw[b2], 1u);
    }
    LDS_FENCE();
    int lo2, hi2; unsigned base2;
    {
        const uint4 hv = *reinterpret_cast<const uint4*>(&hw[l * 4]);
        const unsigned p0 = hv.x, p1 = p0 + hv.y, p2 = p1 + hv.z, p3 = p2 + hv.w;
        unsigned sc = p3;
        #pragma unroll
        for (int off = 1; off < 64; off <<= 1) {
            const unsigned uu = __shfl_up(sc, off);
            if (l >= off) sc += uu;
        }
        const unsigned eb = sc - p3;
        const unsigned cum[4] = {eb + p0, eb + p1, eb + p2, eb + p3};
        int flo = -1, fhi = -1; unsigned fbase = 0u;
        #pragma unroll
        for (int e = 0; e < 4; ++e) {
            const unsigned prev = e ? cum[e - 1] : eb;
            if (cum[e] > k409 && prev <= k409) { flo = l * 4 + e; fbase = prev; }
            if (cum[e] > k410 && prev <= k410) { fhi = l * 4 + e; }
        }
        const unsigned long long bmlo = __ballot(flo >= 0);
        const int srclo = (int)__builtin_ctzll(bmlo);
        lo2 = __shfl(flo, srclo);
        base2 = __shfl(fbase, srclo);
        const unsigned long long bmhi = __ballot(fhi >= 0);
        hi2 = __shfl(fhi, (int)__builtin_ctzll(bmhi));
    }
    // gather2 into c2 (dead hist region) — ballot compaction
    float* c2 = reinterpret_cast<float*>(hw);
    unsigned cnt2 = 0u;
    for (int c0 = 0; c0 < m; c0 += 64) {
        const int ci = c0 + l;
        float v = 0.0f; bool pred = false;
        if (ci < m) {
            v = cw[ci];
            int b2 = (int)(__fmul_rn(__fsub_rn(v, lo_edge), sc2));
            b2 = b2 < 255 ? b2 : 255; b2 = b2 > 0 ? b2 : 0;
            pred = (b2 >= lo2 && b2 <= hi2);
        }
        const unsigned long long bm = __ballot(pred);
        if (pred) {
            const unsigned p = cnt2 + (unsigned)__popcll(bm & ((1ull << l) - 1ull));
            if (p < 256u) c2[p] = v;
        }
        cnt2 += (unsigned)__popcll(bm);
    }
    LDS_FENCE();
    const int c = (int)min(cnt2, 256u);
    const int q409 = (int)(k409 - base2);
    const int q410 = (int)(k410 - base2);
    // result slots (cand region is dead now); deterministic 0 fallback
    if (l == 0) { cw[0] = 0.0f; cw[1] = 0.0f; }
    LDS_FENCE();
    #pragma unroll 1
    for (int cc0 = 0; cc0 < c; cc0 += 64) {
        const int ci = cc0 + l;
        const float v = (ci < c) ? c2[ci] : 0.0f;
        int lt = 0, le = 0;
        #pragma unroll 4
        for (int i = 0; i < c; ++i) {
            const float u = c2[i];
            lt += (u < v) ? 1 : 0;
            le += (u <= v) ? 1 : 0;
        }
        if (ci < c) {
            if (lt <= q409 && q409 < le) cw[0] = v;
            if (lt <= q410 && q410 < le) cw[1] = v;
        }
    }
    LDS_FENCE();
    if (l == 0) {
        // threshold in d-space (head-independent): thD strictly inside the
        // (d409,d410) order-stat gap => {d<=thD} == {d*s <= lerp(d409*s,d410*s)}
        const float d409 = cw[0], d410 = cw[1];
        const float pos = 0.2f * 2047.0f;
        const float g = pos - 409.0f;
        const float lw = 1.0f - g;
        const float thD = __fadd_rn(__fmul_rn(d409, lw), __fmul_rn(d410, g));
        out[(size_t)(b * L_ + rl) * OUTW + 319] = thD;   // scratch, posatt overwrites
    }
}

__global__ __launch_bounds__(512, 8) void posatt_kernel(
    const float* __restrict__ mesh,     // (B,L,2)
    const float* __restrict__ inputs,   // (B,L,D)
    const float* __restrict__ lmda,     // (H)
    const char* __restrict__ ws,        // bf16 chunk-major inputs
    float* __restrict__ out)            // (B,L,320); col 319 holds thD scratch
{
    // phase2 dbuf A+B (2*12320) | epilogue C(8K)
    __shared__ __align__(16) char s_u1[2 * BUFB];     // 24640 B
    __shared__ float s_scale[H_];
    __shared__ float s_thD[RB];
    __shared__ float s_wsum[RB][H_];

    const int t = threadIdx.x;
    const int l = t & 63;
    const int w = t >> 6;               // 8 waves
    const int blk = blockIdx.x;         // 1024
    const int b = blk >> 8;
    const int n0 = (blk & 255) * RB;

    const float2* meshg = reinterpret_cast<const float2*>(mesh) + (size_t)b * L_;

    // per-head scale (exact, verified R2 path)
    if (t < H_) {
        const double lam = (double)lmda[t];
        const float C = (float)(0.25 * M_PI * (1.0 - 1e-07));
        const float s1 = (float)sin(lam);
        const float arg = __fmul_rn(C, __fadd_rn(1.0f, s1));
        s_scale[t] = (float)tan((double)arg);
    }
    // per-row thresholds from scratch slots (this block's own rows only —
    // read precedes this block's writes; other blocks never touch these rows)
    if (t < RB) {
        s_thD[t] = out[(size_t)(b * L_ + n0 + t) * OUTW + 319];
    }
    __syncthreads();

    // ---- phase 2: K-tiled bf16 A-build + MFMA, 1 barrier/tile, dbuf A+B.
    // Mesh read directly from global (L1/L2-resident, 16 KB/batch).
    // A-build thread mapping: jp = j-pair 0..31, rr = row 0..7, h2 = 0..1
    const int jp = t & 31;
    const int rr = (t >> 5) & 7;
    const int h2 = t >> 8;
    const float2 me_b = meshg[n0 + rr];
    const float thD = s_thD[rr];
    constexpr float LOG2E = 1.4426950408889634f;
    const float cA = __fmul_rn(-LOG2E, s_scale[h2]);       // head h2   -> plane 0
    const float cB = __fmul_rn(-LOG2E, s_scale[h2 + 2]);   // head h2+2 -> plane 1
    const int row16 = h2 * 8 + rr;
    const int ks4q_w = jp >> 2;
    const int chunk_w = ks4q_w * 16 + row16;
    const int chunkSw_w = chunk_w ^ (ks4q_w & 7);
    const int aoff0 = (chunkSw_w << 4) + ((jp & 3) << 2);  // plane-0 byte offset
    float waccA = 0.0f, waccB = 0.0f;

    // MFMA-side per-wave mapping (unchanged, layout identical to verified R12)
    const int p_w  = w >> 2;
    const int ks_w = (w >> 1) & 1;
    const int nqh  = w & 1;
    const int ks4q_r = ks_w * 4 + (l >> 4);
    const int chunk_r = ks4q_r * 16 + (l & 15);
    const int aroff = p_w * APS + ((chunk_r ^ (ks4q_r & 7)) << 4);
    f32x4 acc[2];
    acc[0] = (f32x4)0.0f; acc[1] = (f32x4)0.0f;

    const float* inpb = inputs + (size_t)b * L_ * D_;
    const char* wsb = ws + (size_t)b * (L_ * D_ * 2);
    const float4* mesh4 = reinterpret_cast<const float4*>(meshg);
    char* const AE = s_u1;
    char* const BE = s_u1 + ABYTES;
    char* const AO = s_u1 + BUFB;
    char* const BO = s_u1 + BUFB + ABYTES;

    auto LOADB = [&](int tile) -> uint4 {
        return *reinterpret_cast<const uint4*>(wsb + ((size_t)(tile * 512 + t) << 4));
    };
    auto COMMITB = [&](char* Bb, const uint4 bg) {
        *reinterpret_cast<uint4*>(Bb + (t << 4)) = bg;
    };
    auto ABUILD = [&](int tile, char* Ab) {
        const float4 mq = mesh4[tile * 32 + jp];   // mesh points (tile*64+2jp, +1)
        const float dx0 = __fsub_rn(me_b.x, mq.x);
        const float dy0 = __fsub_rn(me_b.y, mq.y);
        const float d0 = __fadd_rn(__fmul_rn(dx0, dx0), __fmul_rn(dy0, dy0));
        const float dx1 = __fsub_rn(me_b.x, mq.z);
        const float dy1 = __fsub_rn(me_b.y, mq.w);
        const float d1 = __fadd_rn(__fmul_rn(dx1, dx1), __fmul_rn(dy1, dy1));
        const bool pass0 = (d0 <= thD);
        const bool pass1 = (d1 <= thD);
        const float wA0 = pass0 ? EXP2F(__fmul_rn(d0, cA)) : 0.0f;
        const float wA1 = pass1 ? EXP2F(__fmul_rn(d1, cA)) : 0.0f;
        const float wB0 = pass0 ? EXP2F(__fmul_rn(d0, cB)) : 0.0f;
        const float wB1 = pass1 ? EXP2F(__fmul_rn(d1, cB)) : 0.0f;
        waccA += __fadd_rn(wA0, wA1);
        waccB += __fadd_rn(wB0, wB1);
        *reinterpret_cast<unsigned*>(Ab + aoff0) = cvt_pk_bf16(wA0, wA1);
        *reinterpret_cast<unsigned*>(Ab + APS + aoff0) = cvt_pk_bf16(wB0, wB1);
    };
    auto MFMA_STEP = [&](const char* Ab, const char* Bb) {
        const bf16x8 afr = *reinterpret_cast<const bf16x8*>(Ab + aroff);
        #pragma unroll
        for (int i = 0; i < 2; ++i) {
            const int nq = nqh * 2 + i;
            const bf16x8 bfr = *reinterpret_cast<const bf16x8*>(
                Bb + (((ks_w * 4 + (l >> 4)) * 64 + nq * 16 + (l & 15)) << 4));
            acc[i] = __builtin_amdgcn_mfma_f32_16x16x32_bf16(afr, bfr, acc[i], 0, 0, 0);
        }
    };

    // prologue: tile 0 into E-buffer
    {
        const uint4 bg0 = LOADB(0);
        ABUILD(0, AE);
        COMMITB(BE, bg0);
    }
    __syncthreads();
    #pragma unroll 1
    for (int tp = 0; tp < NTILE / 2; ++tp) {
        // consume E (tile 2tp), build O (tile 2tp+1); load issued first to hide L2
        uint4 bg = LOADB(2 * tp + 1);
        MFMA_STEP(AE, BE);
        ABUILD(2 * tp + 1, AO);
        COMMITB(BO, bg);
        __syncthreads();
        if (tp < NTILE / 2 - 1) {
            bg = LOADB(2 * tp + 2);
            MFMA_STEP(AO, BO);
            ABUILD(2 * tp + 2, AE);
            COMMITB(BE, bg);
            __syncthreads();
        }
    }
    MFMA_STEP(AO, BO);   // tile 31
    __syncthreads();

    // wsum: reduce over the 32 jp lanes per half-wave; lanes 0/32 write
    waccA += __shfl_xor(waccA, 1);
    waccA += __shfl_xor(waccA, 2);
    waccA += __shfl_xor(waccA, 4);
    waccA += __shfl_xor(waccA, 8);
    waccA += __shfl_xor(waccA, 16);
    waccB += __shfl_xor(waccB, 1);
    waccB += __shfl_xor(waccB, 2);
    waccB += __shfl_xor(waccB, 4);
    waccB += __shfl_xor(waccB, 8);
    waccB += __shfl_xor(waccB, 16);
    if ((l & 31) == 0) {
        s_wsum[rr][h2] = waccA;
        s_wsum[rr][h2 + 2] = waccB;
    }
    // zero C region (8 KB)
    {
        float4* Cz = reinterpret_cast<float4*>(s_u1);
        Cz[t] = make_float4(0.f, 0.f, 0.f, 0.f);
    }
    __syncthreads();
    // reduce k-split accumulator frags into C[32][64]
    {
        float* Cf = reinterpret_cast<float*>(s_u1);
        #pragma unroll
        for (int i = 0; i < 2; ++i) {
            const int nq = nqh * 2 + i;
            #pragma unroll
            for (int reg = 0; reg < 4; ++reg) {
                const int row = (l >> 4) * 4 + reg;
                const int col = nq * 16 + (l & 15);
                atomicAdd(&Cf[(p_w * 16 + row) * 64 + col], acc[i][reg]);
            }
        }
    }
    __syncthreads();
    // normalize + store conv block
    {
        const float* Cf = reinterpret_cast<const float*>(s_u1);
        const int pr = t >> 4;                  // 0..31
        const int p = pr >> 4;
        const int row16o = pr & 15;
        const int h = p * 2 + (row16o >> 3);
        const int r = row16o & 7;
        const int col = (t & 15) << 2;
        const float wsv = s_wsum[r][h];
        const float inv = (wsv != 0.0f) ? 1.0f / wsv : 0.0f;
        float4 r0 = *reinterpret_cast<const float4*>(&Cf[pr * 64 + col]);
        r0.x *= inv; r0.y *= inv; r0.z *= inv; r0.w *= inv;
        float* op = out + (size_t)(b * L_ + n0 + r) * OUTW + D_ + h * 64 + col;
        *reinterpret_cast<float4*>(op) = r0;
    }
    // exact fp32 passthrough of inputs into out[:, :, 0:64]
    {
        const int r = t >> 6;                   // 0..7
        const int c = t & 63;
        out[(size_t)(b * L_ + n0 + r) * OUTW + c] = inpb[(size_t)(n0 + r) * D_ + c];
    }
}

extern "C" void kernel_launch(void* const* d_in, const int* in_sizes, int n_in,
                              void* d_out, int out_size, void* d_ws, size_t ws_size,
                              hipStream_t stream) {
    const float* mesh   = (const float*)d_in[0];
    const float* inputs = (const float*)d_in[1];
    const float* lmda   = (const float*)d_in[2];
    float* out = (float*)d_out;
    char* ws = (char*)d_ws;
    (void)in_sizes; (void)n_in; (void)out_size; (void)ws_size;
    hipLaunchKernelGGL(prep_thresh_kernel, dim3(2048), dim3(256), 0, stream,
                       mesh, inputs, ws, out);
    hipLaunchKernelGGL(posatt_kernel, dim3(B_ * (L_ / RB)), dim3(512), 0, stream,
                       mesh, inputs, lmda, ws, out);
}

// Round 4
// 127.011 us; speedup vs baseline: 1.0122x; 1.0122x over previous
//
#include <hip/hip_runtime.h>
#include <math.h>

#ifndef M_PI
#define M_PI 3.14159265358979323846
#endif

namespace {
constexpr int B_ = 4;
constexpr int L_ = 2048;
constexpr int D_ = 64;
constexpr int H_ = 4;
constexpr int RB = 8;           // rows per block
constexpr int KT = 64;          // K-tile
constexpr int NTILE = L_ / KT;  // 32
constexpr int CAPC = 256;       // per-wave candidate capacity
constexpr int OUTW = D_ + H_ * D_;  // 320
}

typedef __attribute__((ext_vector_type(8))) short bf16x8;
typedef __attribute__((ext_vector_type(4))) float f32x4;

__device__ __forceinline__ unsigned bf16_rne(float x) {
    unsigned u = __float_as_uint(x);
    return (u + 0x7fffu + ((u >> 16) & 1u)) >> 16;
}

// packed f32->bf16 RNE convert (gfx950 HW op)
__device__ __forceinline__ unsigned cvt_pk_bf16(float lo, float hi) {
    unsigned r;
    asm("v_cvt_pk_bf16_f32 %0, %1, %2" : "=v"(r) : "v"(lo), "v"(hi));
    return r;
}

#if defined(__has_builtin)
#if __has_builtin(__builtin_amdgcn_exp2f)
#define EXP2F(x) __builtin_amdgcn_exp2f(x)
#endif
#endif
#ifndef EXP2F
#define EXP2F(x) __expf((x) * 0.69314718055994531f)
#endif

// wait lgkmcnt(0) only (vmcnt=63, expcnt=7)
#define LDS_FENCE() __builtin_amdgcn_s_waitcnt(0xC07F)

// ---- fused prep + per-row threshold kernel (R3-verified verbatim).
// prep: inputs (B,L,D) fp32 -> ws bf16 k-major chunks (128 uints per block).
// thresh: one wave per row; rank-409/410 select; ballot compaction.
// thD written to scratch slot out[row*OUTW + 319] (overwritten by posatt).
__global__ __launch_bounds__(256) void prep_thresh_kernel(
    const float* __restrict__ mesh,
    const float* __restrict__ inputs,
    char* __restrict__ ws,
    float* __restrict__ out)
{
    __shared__ unsigned s_hist[4][256];   // 4 KB (per-wave hist / c2)
    __shared__ float s_cand[4][256];      // 4 KB (per-wave candidates)

    const int t = threadIdx.x;
    const int l = t & 63;
    const int w = t >> 6;                 // 0..3
    const int blk = blockIdx.x;           // 2048

    // ---- prep part: one packed-uint conversion per thread (t<128)
    if (t < 128) {
        const unsigned u = (unsigned)blk * 128u + (unsigned)t;   // < 262144
        const int pb = u >> 16;             // batch
        const int rem = u & 65535;
        const int tile = rem >> 12;         // tile of 128 k
        const int idx = rem & 4095;
        const int n = idx & 63;
        const int kl = (idx >> 6) << 1;     // even k within tile128
        const float* inb = inputs + ((size_t)pb * L_ + tile * 128) * D_;
        char* wsb = ws + (size_t)pb * (L_ * D_ * 2) + tile * (128 * D_ * 2);
        const float x0 = inb[kl * D_ + n];
        const float x1 = inb[(kl + 1) * D_ + n];
        const int chunk = (kl >> 3) * 64 + n;
        const int e = kl & 7;
        *reinterpret_cast<unsigned*>(wsb + chunk * 16 + e * 2) =
            bf16_rne(x0) | (bf16_rne(x1) << 16);
    }

    // ---- thresh part: this wave's row
    const int row = blk * 4 + w;          // 0..8191
    const int b = row >> 11;
    const int rl = row & 2047;
    const float2* meshg = reinterpret_cast<const float2*>(mesh) + (size_t)b * L_;
    unsigned* hw = s_hist[w];
    float* cw = s_cand[w];
    const float2 me = meshg[rl];

    *reinterpret_cast<uint4*>(&hw[l * 4]) = make_uint4(0u, 0u, 0u, 0u);
    LDS_FENCE();
    #pragma unroll 4
    for (int it = 0; it < 32; ++it) {
        const int j = (it << 6) + l;
        const float2 mj = meshg[j];
        const float dx = __fsub_rn(me.x, mj.x);
        const float dy = __fsub_rn(me.y, mj.y);
        const float d = __fadd_rn(__fmul_rn(dx, dx), __fmul_rn(dy, dy));
        int bin = (int)(d * 128.0f); bin = bin < 255 ? bin : 255;
        atomicAdd(&hw[bin], 1u);
    }
    LDS_FENCE();
    // level-1 scan + crossings at ranks 409/410
    int lo, hi; unsigned base;
    {
        const uint4 hv = *reinterpret_cast<const uint4*>(&hw[l * 4]);
        const unsigned p0 = hv.x, p1 = p0 + hv.y, p2 = p1 + hv.z, p3 = p2 + hv.w;
        unsigned sc = p3;
        #pragma unroll
        for (int off = 1; off < 64; off <<= 1) {
            const unsigned uu = __shfl_up(sc, off);
            if (l >= off) sc += uu;
        }
        const unsigned eb = sc - p3;
        const unsigned cum[4] = {eb + p0, eb + p1, eb + p2, eb + p3};
        int flo = -1, fhi = -1; unsigned fbase = 0u;
        #pragma unroll
        for (int e = 0; e < 4; ++e) {
            const unsigned prev = e ? cum[e - 1] : eb;
            if (cum[e] > 409u && prev <= 409u) { flo = l * 4 + e; fbase = prev; }
            if (cum[e] > 410u && prev <= 410u) { fhi = l * 4 + e; }
        }
        const unsigned long long bmlo = __ballot(flo >= 0);
        const int srclo = (int)__builtin_ctzll(bmlo);
        lo = __shfl(flo, srclo);
        base = __shfl(fbase, srclo);
        const unsigned long long bmhi = __ballot(fhi >= 0);
        hi = __shfl(fhi, (int)__builtin_ctzll(bmhi));
    }
    // gather candidates from bins [lo,hi] — ballot compaction (no atomics)
    unsigned cbase = 0u;
    #pragma unroll 4
    for (int it = 0; it < 32; ++it) {
        const int j = (it << 6) + l;
        const float2 mj = meshg[j];
        const float dx = __fsub_rn(me.x, mj.x);
        const float dy = __fsub_rn(me.y, mj.y);
        const float d = __fadd_rn(__fmul_rn(dx, dx), __fmul_rn(dy, dy));
        int bin = (int)(d * 128.0f); bin = bin < 255 ? bin : 255;
        const bool pred = (bin >= lo && bin <= hi);
        const unsigned long long bm = __ballot(pred);
        if (pred) {
            const unsigned p = cbase + (unsigned)__popcll(bm & ((1ull << l) - 1ull));
            if (p < (unsigned)CAPC) cw[p] = d;
        }
        cbase += (unsigned)__popcll(bm);
    }
    LDS_FENCE();
    const int m = (int)min(cbase, (unsigned)CAPC);
    const unsigned k409 = 409u - base;      // rank within cw
    const unsigned k410 = 410u - base;
    // ---- level-2 refine: 256 sub-bins over candidate range
    const float lo_edge = (float)lo * 0.0078125f;          // lo/128, exact
    const float sc2 = 32768.0f / (float)(hi - lo + 1);     // 256*128/(span bins)
    *reinterpret_cast<uint4*>(&hw[l * 4]) = make_uint4(0u, 0u, 0u, 0u);
    LDS_FENCE();
    #pragma unroll 2
    for (int ci = l; ci < m; ci += 64) {
        const float v = cw[ci];
        int b2 = (int)(__fmul_rn(__fsub_rn(v, lo_edge), sc2));
        b2 = b2 < 255 ? b2 : 255; b2 = b2 > 0 ? b2 : 0;
        atomicAdd(&hw[b2], 1u);
    }
    LDS_FENCE();
    int lo2, hi2; unsigned base2;
    {
        const uint4 hv = *reinterpret_cast<const uint4*>(&hw[l * 4]);
        const unsigned p0 = hv.x, p1 = p0 + hv.y, p2 = p1 + hv.z, p3 = p2 + hv.w;
        unsigned sc = p3;
        #pragma unroll
        for (int off = 1; off < 64; off <<= 1) {
            const unsigned uu = __shfl_up(sc, off);
            if (l >= off) sc += uu;
        }
        const unsigned eb = sc - p3;
        const unsigned cum[4] = {eb + p0, eb + p1, eb + p2, eb + p3};
        int flo = -1, fhi = -1; unsigned fbase = 0u;
        #pragma unroll
        for (int e = 0; e < 4; ++e) {
            const unsigned prev = e ? cum[e - 1] : eb;
            if (cum[e] > k409 && prev <= k409) { flo = l * 4 + e; fbase = prev; }
            if (cum[e] > k410 && prev <= k410) { fhi = l * 4 + e; }
        }
        const unsigned long long bmlo = __ballot(flo >= 0);
        const int srclo = (int)__builtin_ctzll(bmlo);
        lo2 = __shfl(flo, srclo);
        base2 = __shfl(fbase, srclo);
        const unsigned long long bmhi = __ballot(fhi >= 0);
        hi2 = __shfl(fhi, (int)__builtin_ctzll(bmhi));
    }
    // gather2 into c2 (dead hist region) — ballot compaction
    float* c2 = reinterpret_cast<float*>(hw);
    unsigned cnt2 = 0u;
    for (int c0 = 0; c0 < m; c0 += 64) {
        const int ci = c0 + l;
        float v = 0.0f; bool pred = false;
        if (ci < m) {
            v = cw[ci];
            int b2 = (int)(__fmul_rn(__fsub_rn(v, lo_edge), sc2));
            b2 = b2 < 255 ? b2 : 255; b2 = b2 > 0 ? b2 : 0;
            pred = (b2 >= lo2 && b2 <= hi2);
        }
        const unsigned long long bm = __ballot(pred);
        if (pred) {
            const unsigned p = cnt2 + (unsigned)__popcll(bm & ((1ull << l) - 1ull));
            if (p < 256u) c2[p] = v;
        }
        cnt2 += (unsigned)__popcll(bm);
    }
    LDS_FENCE();
    const int c = (int)min(cnt2, 256u);
    const int q409 = (int)(k409 - base2);
    const int q410 = (int)(k410 - base2);
    // result slots (cand region is dead now); deterministic 0 fallback
    if (l == 0) { cw[0] = 0.0f; cw[1] = 0.0f; }
    LDS_FENCE();
    #pragma unroll 1
    for (int cc0 = 0; cc0 < c; cc0 += 64) {
        const int ci = cc0 + l;
        const float v = (ci < c) ? c2[ci] : 0.0f;
        int lt = 0, le = 0;
        #pragma unroll 4
        for (int i = 0; i < c; ++i) {
            const float u = c2[i];
            lt += (u < v) ? 1 : 0;
            le += (u <= v) ? 1 : 0;
        }
        if (ci < c) {
            if (lt <= q409 && q409 < le) cw[0] = v;
            if (lt <= q410 && q410 < le) cw[1] = v;
        }
    }
    LDS_FENCE();
    if (l == 0) {
        // threshold in d-space (head-independent): thD strictly inside the
        // (d409,d410) order-stat gap => {d<=thD} == {d*s <= lerp(d409*s,d410*s)}
        const float d409 = cw[0], d410 = cw[1];
        const float pos = 0.2f * 2047.0f;
        const float g = pos - 409.0f;
        const float lw = 1.0f - g;
        const float thD = __fadd_rn(__fmul_rn(d409, lw), __fmul_rn(d410, g));
        out[(size_t)(b * L_ + rl) * OUTW + 319] = thD;   // scratch, posatt overwrites
    }
}

// ---- posatt: barrier-free main loop. 4 waves = 2 planes x 2 k-splits;
// each wave computes its A fragment in-register (exact verified math) and
// loads B fragments directly from ws global (verified chunk offsets).
// No LDS, no __syncthreads in the 32-tile loop.
__global__ __launch_bounds__(256, 4) void posatt_kernel(
    const float* __restrict__ mesh,     // (B,L,2)
    const float* __restrict__ inputs,   // (B,L,D)
    const float* __restrict__ lmda,     // (H)
    const char* __restrict__ ws,        // bf16 chunk-major inputs
    float* __restrict__ out)            // (B,L,320); col 319 holds thD scratch
{
    __shared__ float s_C[32 * 64];      // 8 KB epilogue reduction
    __shared__ float s_scale[H_];
    __shared__ float s_thD[RB];
    __shared__ float s_ws2[2][2][16];   // [ks][plane][row16]

    const int t = threadIdx.x;          // 256 threads
    const int l = t & 63;
    const int w = t >> 6;               // 0..3
    const int p_w  = w >> 1;            // plane (head-pair)
    const int ks_w = w & 1;             // k-split half (32 of 64)

    // bijective XCD swizzle: 2 XCDs per batch -> per-XCD L2 holds one 2MB ws
    const int blk = blockIdx.x;         // 1024
    const int xcd = blk & 7;
    const int b = xcd >> 1;
    const int n0 = (((xcd & 1) << 7) + (blk >> 3)) * RB;

    const float2* meshg = reinterpret_cast<const float2*>(mesh) + (size_t)b * L_;

    // per-head scale (exact, verified R2 path)
    if (t < H_) {
        const double lam = (double)lmda[t];
        const float C = (float)(0.25 * M_PI * (1.0 - 1e-07));
        const float s1 = (float)sin(lam);
        const float arg = __fmul_rn(C, __fadd_rn(1.0f, s1));
        s_scale[t] = (float)tan((double)arg);
    }
    // per-row thresholds from scratch slots (own rows only; read precedes write)
    if (t < RB) {
        s_thD[t] = out[(size_t)(b * L_ + n0 + t) * OUTW + 319];
    }
    __syncthreads();

    const int row16 = l & 15;           // MFMA A row: head-half * 8 + mesh-row
    const int kq = l >> 4;              // k-quad 0..3
    const int rl = row16 & 7;           // mesh row within block
    const float2 me = meshg[n0 + rl];
    const float thD = s_thD[rl];
    constexpr float LOG2E = 1.4426950408889634f;
    const float cH = __fmul_rn(-LOG2E, s_scale[p_w * 2 + (row16 >> 3)]);

    // B: global chunk base for this lane; chunk c(nq) = (ks*4+kq)*64 + nq*16 + row16
    const char* bptr = ws + (size_t)b * (L_ * D_ * 2)
                     + ((size_t)(((ks_w * 4 + kq) * 64) + row16) << 4);
    // mesh pairs for this lane's 8 k-values: points ks*32 + kq*8 .. +7
    const float4* mptr = reinterpret_cast<const float4*>(meshg) + (ks_w * 16 + kq * 4);

    f32x4 acc[4];
    acc[0] = (f32x4)0.0f; acc[1] = (f32x4)0.0f;
    acc[2] = (f32x4)0.0f; acc[3] = (f32x4)0.0f;
    float wacc = 0.0f;

    uint4 cb0, cb1, cb2, cb3;
    float4 cm0, cm1, cm2, cm3;
    auto LOADT = [&](int tl, uint4& B0, uint4& B1, uint4& B2, uint4& B3,
                     float4& M0, float4& M1, float4& M2, float4& M3) {
        const char* p = bptr + ((size_t)tl << 13);     // tile*512 chunks*16B
        B0 = *reinterpret_cast<const uint4*>(p);
        B1 = *reinterpret_cast<const uint4*>(p + 256); // +16 chunks (next quad)
        B2 = *reinterpret_cast<const uint4*>(p + 512);
        B3 = *reinterpret_cast<const uint4*>(p + 768);
        const float4* q = mptr + tl * 32;
        M0 = q[0]; M1 = q[1]; M2 = q[2]; M3 = q[3];
    };
    auto DW = [&](float mx, float my) -> float {
        const float dx = __fsub_rn(me.x, mx);
        const float dy = __fsub_rn(me.y, my);
        const float d = __fadd_rn(__fmul_rn(dx, dx), __fmul_rn(dy, dy));
        const float x = __fmul_rn(d, cH);
        return (d <= thD) ? EXP2F(x) : 0.0f;
    };
    auto STEP = [&]() {
        const float w0 = DW(cm0.x, cm0.y), w1 = DW(cm0.z, cm0.w);
        const float w2 = DW(cm1.x, cm1.y), w3 = DW(cm1.z, cm1.w);
        const float w4 = DW(cm2.x, cm2.y), w5 = DW(cm2.z, cm2.w);
        const float w6 = DW(cm3.x, cm3.y), w7 = DW(cm3.z, cm3.w);
        wacc = __fadd_rn(wacc,
            __fadd_rn(__fadd_rn(__fadd_rn(w0, w1), __fadd_rn(w2, w3)),
                      __fadd_rn(__fadd_rn(w4, w5), __fadd_rn(w6, w7))));
        union { uint4 u; bf16x8 v; } av;
        av.u = make_uint4(cvt_pk_bf16(w0, w1), cvt_pk_bf16(w2, w3),
                          cvt_pk_bf16(w4, w5), cvt_pk_bf16(w6, w7));
        union { uint4 u; bf16x8 v; } b0v, b1v, b2v, b3v;
        b0v.u = cb0; b1v.u = cb1; b2v.u = cb2; b3v.u = cb3;
        acc[0] = __builtin_amdgcn_mfma_f32_16x16x32_bf16(av.v, b0v.v, acc[0], 0, 0, 0);
        acc[1] = __builtin_amdgcn_mfma_f32_16x16x32_bf16(av.v, b1v.v, acc[1], 0, 0, 0);
        acc[2] = __builtin_amdgcn_mfma_f32_16x16x32_bf16(av.v, b2v.v, acc[2], 0, 0, 0);
        acc[3] = __builtin_amdgcn_mfma_f32_16x16x32_bf16(av.v, b3v.v, acc[3], 0, 0, 0);
    };

    LOADT(0, cb0, cb1, cb2, cb3, cm0, cm1, cm2, cm3);
    #pragma unroll 1
    for (int tl = 0; tl < NTILE - 1; ++tl) {
        uint4 nb0, nb1, nb2, nb3;
        float4 nm0, nm1, nm2, nm3;
        LOADT(tl + 1, nb0, nb1, nb2, nb3, nm0, nm1, nm2, nm3);
        STEP();
        cb0 = nb0; cb1 = nb1; cb2 = nb2; cb3 = nb3;
        cm0 = nm0; cm1 = nm1; cm2 = nm2; cm3 = nm3;
    }
    STEP();   // tile 31

    // wsum: reduce over the 4 k-quad lane-groups (same row16)
    wacc += __shfl_xor(wacc, 16);
    wacc += __shfl_xor(wacc, 32);
    if (l < 16) s_ws2[ks_w][p_w][l] = wacc;
    // zero C region (8 KB)
    {
        float4* Cz = reinterpret_cast<float4*>(s_C);
        Cz[t] = make_float4(0.f, 0.f, 0.f, 0.f);
        Cz[t + 256] = make_float4(0.f, 0.f, 0.f, 0.f);
    }
    __syncthreads();
    // reduce k-split accumulator frags into C[32][64]
    #pragma unroll
    for (int nq = 0; nq < 4; ++nq) {
        #pragma unroll
        for (int reg = 0; reg < 4; ++reg) {
            const int row = kq * 4 + reg;
            const int col = nq * 16 + row16;
            atomicAdd(&s_C[(p_w * 16 + row) * 64 + col], acc[nq][reg]);
        }
    }
    __syncthreads();
    // normalize + store conv block + exact fp32 passthrough
    const float* inpb = inputs + (size_t)b * L_ * D_;
    #pragma unroll
    for (int half = 0; half < 2; ++half) {
        const int s = t + half * 256;       // 0..511
        const int pr = s >> 4;              // 0..31
        const int p = pr >> 4;
        const int r16 = pr & 15;
        const int h = p * 2 + (r16 >> 3);
        const int r = r16 & 7;
        const int col = (s & 15) << 2;
        const float wsv = s_ws2[0][p][r16] + s_ws2[1][p][r16];
        const float inv = (wsv != 0.0f) ? 1.0f / wsv : 0.0f;
        float4 r0 = *reinterpret_cast<const float4*>(&s_C[pr * 64 + col]);
        r0.x *= inv; r0.y *= inv; r0.z *= inv; r0.w *= inv;
        float* op = out + (size_t)(b * L_ + n0 + r) * OUTW + D_ + h * 64 + col;
        *reinterpret_cast<float4*>(op) = r0;
        // passthrough: out[:, :, 0:64] = inputs
        const int rr2 = s >> 6;             // 0..7
        const int cc2 = s & 63;
        out[(size_t)(b * L_ + n0 + rr2) * OUTW + cc2] =
            inpb[(size_t)(n0 + rr2) * D_ + cc2];
    }
}

extern "C" void kernel_launch(void* const* d_in, const int* in_sizes, int n_in,
                              void* d_out, int out_size, void* d_ws, size_t ws_size,
                              hipStream_t stream) {
    const float* mesh   = (const float*)d_in[0];
    const float* inputs = (const float*)d_in[1];
    const float* lmda   = (const float*)d_in[2];
    float* out = (float*)d_out;
    char* ws = (char*)d_ws;
    (void)in_sizes; (void)n_in; (void)out_size; (void)ws_size;
    hipLaunchKernelGGL(prep_thresh_kernel, dim3(2048), dim3(256), 0, stream,
                       mesh, inputs, ws, out);
    hipLaunchKernelGGL(posatt_kernel, dim3(B_ * (L_ / RB)), dim3(256), 0, stream,
                       mesh, inputs, lmda, ws, out);
}